// Round 11
// baseline (178.669 us; speedup 1.0000x reference)
//
#include <hip/hip_runtime.h>
#include <cmath>

// CXLoss pipeline, revision 29: R27 base + single-barrier triple-buffer loop.
// R28 (K_A=2) regressed (178.1 vs 173.3) -- with R26 that's two independent
// falsifications: per-iter overhead scales with content, not iter count.
// Residual binder theory: TWO barrier rendezvous per iter serialize the
// phases. Fix: Ab[3] triple buffer -> stage(it+2) never touches the buffer
// being read (it%3) or read next ((it+1)%3); every wave reaches barrier it+1
// only after its iter-it ds_reads landed (lgkm before its MFMAs), so ONE
// barrier/iter is race-free. w_lgkm + bar#2 deleted. vmcnt counts unchanged
// (vm4 steady / vm0 last). Plus T5 setprio(1) around MFMA clusters (2
// independent blocks/CU = role diversity, the regime where setprio pays).

#define NB 4
#define CC 256
#define HW 4096
#define NQ0 8    // p-slab loop-split (CMAX/WSUM partials)
#define NCS 16   // q col-strips (MAXP partials)

static constexpr float kEPS = 1e-8f;
static constexpr float kSIG = 0.1f + 1e-8f;

typedef __attribute__((ext_vector_type(8)))  short short8;
typedef __attribute__((ext_vector_type(16))) float f32x16;

// workspace layout (float units)
enum {
  OFF_MEAN = 0,                        // 256 channel means
  OFF_CMAX = 256,                      // NQ0*NB*HW colmax partials
  OFF_WSUM = OFF_CMAX + NQ0*NB*HW,     // NQ0*NB*HW Wsum partials
  OFF_MAXP = OFF_WSUM + NQ0*NB*HW,     // NCS*NB*HW maxv partials (1MB)
  OFF_MAXV = OFF_MAXP + NCS*NB*HW,     // NB*HW maxv
  OFF_GT   = OFF_MAXV + NB*HW,         // NB*HW*CC bf16, fragment-tiled
  OFF_GI   = OFF_GT + NB*HW*CC/2,
  WS_FLOATS_FULL = OFF_GI + NB*HW*CC/2
};

__device__ __forceinline__ ushort cvt_bf16(float x) {
  unsigned u = __float_as_uint(x);
  unsigned r = (u + 0x7fffu + ((u >> 16) & 1u)) >> 16;  // round-nearest-even
  return (ushort)r;
}

__device__ __forceinline__ void glds16(const ushort* g, ushort* l) {
  __builtin_amdgcn_global_load_lds(
      (const __attribute__((address_space(1))) unsigned*)g,
      (__attribute__((address_space(3))) unsigned*)l, 16, 0, 0);
}
__device__ __forceinline__ void s_bar()  { asm volatile("s_barrier" ::: "memory"); }
__device__ __forceinline__ void w_vm4()  { asm volatile("s_waitcnt vmcnt(4)" ::: "memory"); }
__device__ __forceinline__ void w_vm0()  { asm volatile("s_waitcnt vmcnt(0)" ::: "memory"); }

__device__ __forceinline__ float blockSum256(float v) {
  __shared__ float sh[4];
  const int lane = threadIdx.x & 63, wv = threadIdx.x >> 6;
  #pragma unroll
  for (int o = 32; o > 0; o >>= 1) v += __shfl_down(v, o, 64);
  __syncthreads();
  if (lane == 0) sh[wv] = v;
  __syncthreads();
  return sh[0] + sh[1] + sh[2] + sh[3];
}

// K1: per-channel mean of featureT. grid=256
__global__ __launch_bounds__(256) void k_mean9(const float* __restrict__ fT,
                                               float* __restrict__ ws) {
  const int c = blockIdx.x, t = threadIdx.x;
  float s = 0.f;
  for (int n = 0; n < NB; ++n) {
    const float* p = fT + (size_t)(n*CC + c)*HW;
    #pragma unroll
    for (int k = 0; k < 16; ++k) s += p[k*256 + t];
  }
  const float tot = blockSum256(s);
  if (t == 0) ws[OFF_MEAN + c] = tot * (1.0f/16384.0f);
}

// K2: fused normalize + fragment-tiled bf16 write (verified R14 layout):
// offset_ushort(n, r32, kc) = ((n*128 + r32)*16 + kc)*512 + l*8
//   holds X[n][p = r32*32 + (l&31)][c = kc*16 + (l>>5)*8 + j], j<8.
// grid = 2 * NB * 128 = 1024 blocks.
__global__ __launch_bounds__(256) void k_prep9(const float* __restrict__ fT,
                                               const float* __restrict__ fI,
                                               float* __restrict__ ws) {
  __shared__ float stage[32][257];
  __shared__ float prt[8][32];
  __shared__ float sinv[32];
  const int t = threadIdx.x, l = t & 63;
  int bid = blockIdx.x;
  const int tensor = (bid >= 512); bid &= 511;
  const int n   = bid >> 7;
  const int r32 = bid & 127;
  const int p0  = r32 * 32;

  const float* __restrict__ src = tensor ? fI : fT;
  ushort* __restrict__ dst = (ushort*)(ws + (tensor ? OFF_GI : OFF_GT));
  const float* __restrict__ mean = ws + OFF_MEAN;

  const int pl = t & 31, cg = t >> 5;
  float acc = 0.f;
  #pragma unroll
  for (int i = 0; i < 32; ++i) {
    const int c = cg*32 + i;
    const float v = src[((size_t)(n*CC + c))*HW + p0 + pl] - mean[c];
    stage[pl][c] = v;
    acc += v*v;
  }
  prt[cg][pl] = acc;
  __syncthreads();
  if (t < 32) {
    float s = 0.f;
    #pragma unroll
    for (int g = 0; g < 8; ++g) s += prt[g][t];
    sinv[t] = 1.0f/(sqrtf(s) + kEPS);
  }
  __syncthreads();

  const int w = t >> 6, lhi = l >> 5, m = l & 31;
  const float iv = sinv[m];
  #pragma unroll
  for (int i = 0; i < 4; ++i) {
    const int kc = w*4 + i;
    const int cb = kc*16 + lhi*8;
    short8 o;
    #pragma unroll
    for (int j = 0; j < 8; ++j)
      ((ushort*)&o)[j] = cvt_bf16(stage[m][cb + j] * iv);
    *(short8*)(dst + (((size_t)(n*128 + r32)*16 + kc) << 9) + l*8) = o;
  }
}

// ---- shared sweep geometry (K_B=2, glds + counted vmcnt, 1 barrier/iter) ----
// L: xcd = L&7, g = L>>3; nh = xcd*4 + (g&3); cs = g>>2.
// n = nh>>3, h = nh&7, col0 = cs*256.
// Ab[3] rotation: tile it read from buf it%3; stage(it+2) -> buf (it+2)%3.
// vmcnt(4) steady (one tile in flight), vmcnt(0) last iter.
// wave w: B col-tiles RB0 = cs*8+w, RB1 = cs*8+4+w.
// C/D map: col = lane&31, row = (r&3) + 8*(r>>2) + 4*(lane>>5).

#define SWEEP_IDS                                                             \
  const int t = threadIdx.x;                                                  \
  const int w = t >> 6, l = t & 63;                                           \
  const int ln31 = l & 31, lhi = l >> 5;  (void)lhi;                          \
  const int L = blockIdx.x;                                                   \
  const int xcd = L & 7, g = L >> 3;                                          \
  const int nh = xcd*4 + (g & 3);                                             \
  const int cs = g >> 2;                                                      \
  const int n = nh >> 3, h = nh & 7;                                          \
  const int col0 = cs * 256;

#define LOAD_BREG                                                             \
  short8 breg0[16], breg1[16];                                                \
  {                                                                           \
    const int RB0 = cs*8 + w, RB1 = cs*8 + 4 + w;                             \
    _Pragma("unroll")                                                         \
    for (int kc = 0; kc < 16; ++kc) {                                         \
      breg0[kc] = *(const short8*)(gB + (((size_t)(n*128 + RB0)*16 + kc) << 9) + l*8); \
      breg1[kc] = *(const short8*)(gB + (((size_t)(n*128 + RB1)*16 + kc) << 9) + l*8); \
    }                                                                         \
  }

#define STAGE_TILE(it_, buf_)                                                 \
  {                                                                           \
    const ushort* __restrict__ srcg = gAn + ((size_t)(it_) << 13);            \
    ushort* __restrict__ dstl = &Ab[buf_][0];                                 \
    _Pragma("unroll")                                                         \
    for (int i = 0; i < 4; ++i)                                               \
      glds16(srcg + (size_t)(i*256 + t)*8, dstl + (i*256 + t)*8);             \
  }

// K3a: GEMM sweep + colmax partials. grid 512.
__global__ __launch_bounds__(256, 2) void k_gA(
    const ushort* __restrict__ gA, const ushort* __restrict__ gB,
    float* __restrict__ ws)
{
  __shared__ ushort Ab[3][8192];    // 24KB triple buffer
  __shared__ float red2[256];

  SWEEP_IDS
  const ushort* __restrict__ gAn = gA + ((size_t)(n*128 + h*16) << 13);

  STAGE_TILE(0, 0)
  STAGE_TILE(1, 1)
  LOAD_BREG

  float run0 = -3.0e38f, run1 = -3.0e38f;

  int cur = 0, nxt2 = 2;            // it%3, (it+2)%3
  for (int iter = 0; iter < 16; ++iter) {
    if (iter < 15) w_vm4(); else w_vm0();
    s_bar();                                   // tile iter staged; buf nxt2 free

    if (iter + 2 < 16) STAGE_TILE(iter + 2, nxt2)

    const ushort* __restrict__ Abuf = &Ab[cur][0];
    f32x16 acc0, acc1;
    #pragma unroll
    for (int e = 0; e < 16; ++e) { acc0[e] = 0.f; acc1[e] = 0.f; }
    __builtin_amdgcn_s_setprio(1);
    #pragma unroll
    for (int kc = 0; kc < 16; ++kc) {
      const short8 a0 = *(const short8*)&Abuf[kc*512 + l*8];
      acc0 = __builtin_amdgcn_mfma_f32_32x32x16_bf16(a0, breg0[kc], acc0, 0, 0, 0);
      acc1 = __builtin_amdgcn_mfma_f32_32x32x16_bf16(a0, breg1[kc], acc1, 0, 0, 0);
    }
    __builtin_amdgcn_s_setprio(0);

    #pragma unroll
    for (int r = 0; r < 16; ++r) {
      run0 = fmaxf(run0, acc0[r]);
      run1 = fmaxf(run1, acc1[r]);
    }
    cur  = (cur  == 2) ? 0 : cur + 1;
    nxt2 = (nxt2 == 2) ? 0 : nxt2 + 1;
  }

  run0 = fmaxf(run0, __shfl_xor(run0, 32, 64));
  run1 = fmaxf(run1, __shfl_xor(run1, 32, 64));
  if (l < 32) {
    red2[w*32 + ln31]       = run0;
    red2[128 + w*32 + ln31] = run1;
  }
  __syncthreads();
  ws[OFF_CMAX + h*(NB*HW) + n*HW + col0 + t] = red2[t];
}

// K3b: GEMM sweep + Wsum partials. Per-lane a,b derived from CMAX.
__global__ __launch_bounds__(256, 2) void k_gB(
    const ushort* __restrict__ gA, const ushort* __restrict__ gB,
    float* __restrict__ ws)
{
  __shared__ ushort Ab[3][8192];
  __shared__ float red2[256];

  SWEEP_IDS
  const ushort* __restrict__ gAn = gA + ((size_t)(n*128 + h*16) << 13);

  STAGE_TILE(0, 0)
  STAGE_TILE(1, 1)

  // per-lane affine coeffs for both q columns (same op order as R27)
  float aq0, bq0, aq1, bq1;
  {
    const int q0 = col0 + w*32 + ln31;
    const int q1 = q0 + 128;
    float cm0 = -3.0e38f, cm1 = -3.0e38f;
    #pragma unroll
    for (int hh = 0; hh < NQ0; ++hh) {
      cm0 = fmaxf(cm0, ws[OFF_CMAX + hh*(NB*HW) + n*HW + q0]);
      cm1 = fmaxf(cm1, ws[OFF_CMAX + hh*(NB*HW) + n*HW + q1]);
    }
    const float i0 = 1.0f/(2.0f*(0.5f*(1.0f - cm0) + kEPS));
    const float i1 = 1.0f/(2.0f*(0.5f*(1.0f - cm1) + kEPS));
    bq0 = i0 / kSIG; aq0 = (1.0f - i0) / kSIG;
    bq1 = i1 / kSIG; aq1 = (1.0f - i1) / kSIG;
  }

  LOAD_BREG

  float ws0 = 0.f, ws1 = 0.f;

  int cur = 0, nxt2 = 2;
  for (int iter = 0; iter < 16; ++iter) {
    if (iter < 15) w_vm4(); else w_vm0();
    s_bar();

    if (iter + 2 < 16) STAGE_TILE(iter + 2, nxt2)

    const ushort* __restrict__ Abuf = &Ab[cur][0];
    f32x16 acc0, acc1;
    #pragma unroll
    for (int e = 0; e < 16; ++e) { acc0[e] = 0.f; acc1[e] = 0.f; }
    __builtin_amdgcn_s_setprio(1);
    #pragma unroll
    for (int kc = 0; kc < 16; ++kc) {
      const short8 a0 = *(const short8*)&Abuf[kc*512 + l*8];
      acc0 = __builtin_amdgcn_mfma_f32_32x32x16_bf16(a0, breg0[kc], acc0, 0, 0, 0);
      acc1 = __builtin_amdgcn_mfma_f32_32x32x16_bf16(a0, breg1[kc], acc1, 0, 0, 0);
    }
    __builtin_amdgcn_s_setprio(0);

    #pragma unroll
    for (int r = 0; r < 16; ++r) {
      ws0 += __expf(fmaf(bq0, acc0[r], aq0));
      ws1 += __expf(fmaf(bq1, acc1[r], aq1));
    }
    cur  = (cur  == 2) ? 0 : cur + 1;
    nxt2 = (nxt2 == 2) ? 0 : nxt2 + 1;
  }

  ws0 += __shfl_xor(ws0, 32, 64);
  ws1 += __shfl_xor(ws1, 32, 64);
  if (l < 32) {
    red2[w*32 + ln31]       = ws0;
    red2[128 + w*32 + ln31] = ws1;
  }
  __syncthreads();
  ws[OFF_WSUM + h*(NB*HW) + n*HW + col0 + t] = red2[t];
}

// K3c: GEMM sweep + row-max (maxv) partials, SWAPPED operands (R27 scheme):
// acc = mfma(breg, afrag) -> col(lane&31) = p, reg = q. Max over q in-register
// + one shfl_xor(32). gamma/beta per q-row from per-block LDS table.
__global__ __launch_bounds__(256, 2) void k_gC(
    const ushort* __restrict__ gA, const ushort* __restrict__ gB,
    float* __restrict__ ws)
{
  __shared__ ushort Ab[3][8192];
  __shared__ float gam_s[256], bet_s[256];
  __shared__ float stash[4][512];   // 8KB: per-wave p-maxima

  SWEEP_IDS
  const ushort* __restrict__ gAn = gA + ((size_t)(n*128 + h*16) << 13);

  STAGE_TILE(0, 0)
  STAGE_TILE(1, 1)

  // gamma/beta table for this block's 256 q (formula/order == old k_gb9)
  {
    const int idx = n*HW + col0 + t;
    float cm = -3.0e38f;
    #pragma unroll
    for (int hh = 0; hh < NQ0; ++hh)
      cm = fmaxf(cm, ws[OFF_CMAX + hh*(NB*HW) + idx]);
    float sw = 0.f;
    #pragma unroll
    for (int hh = 0; hh < NQ0; ++hh)
      sw += ws[OFF_WSUM + hh*(NB*HW) + idx];
    const float i0 = 1.0f/(2.0f*(0.5f*(1.0f - cm) + kEPS));
    bet_s[t] = i0 / kSIG;
    gam_s[t] = (1.0f - i0) / kSIG - logf(sw + kEPS);
  }

  LOAD_BREG
  __syncthreads();   // gam/bet table ready

  int cur = 0, nxt2 = 2;
  for (int iter = 0; iter < 16; ++iter) {
    if (iter < 15) w_vm4(); else w_vm0();
    s_bar();                                   // Ab[cur] staged

    if (iter + 2 < 16) STAGE_TILE(iter + 2, nxt2)

    const ushort* __restrict__ Abuf = &Ab[cur][0];
    f32x16 accq0, accq1;                       // rows = q, cols = p (swapped)
    #pragma unroll
    for (int e = 0; e < 16; ++e) { accq0[e] = 0.f; accq1[e] = 0.f; }
    __builtin_amdgcn_s_setprio(1);
    #pragma unroll
    for (int kc = 0; kc < 16; ++kc) {
      const short8 a0 = *(const short8*)&Abuf[kc*512 + l*8];
      accq0 = __builtin_amdgcn_mfma_f32_32x32x16_bf16(breg0[kc], a0, accq0, 0, 0, 0);
      accq1 = __builtin_amdgcn_mfma_f32_32x32x16_bf16(breg1[kc], a0, accq1, 0, 0, 0);
    }
    __builtin_amdgcn_s_setprio(0);

    // epilogue: lane holds p = iter*32 + ln31; 16 q-rows per acc tile.
    float m = -3.0e38f;
    #pragma unroll
    for (int r = 0; r < 16; ++r) {
      const int row = (r & 3) + 8*(r >> 2) + 4*lhi;
      const float g0v = gam_s[w*32 + row],       b0v = bet_s[w*32 + row];
      const float g1v = gam_s[128 + w*32 + row], b1v = bet_s[128 + w*32 + row];
      m = fmaxf(m, fmaf(b0v, accq0[r], g0v));
      m = fmaxf(m, fmaf(b1v, accq1[r], g1v));
    }
    m = fmaxf(m, __shfl_xor(m, 32, 64));       // merge lhi q-halves
    if (l < 32) stash[w][iter*32 + ln31] = m;  // p-local = iter*32 + ln31

    cur  = (cur  == 2) ? 0 : cur + 1;
    nxt2 = (nxt2 == 2) ? 0 : nxt2 + 1;
  }

  __syncthreads();
  float* __restrict__ MAXP = ws + OFF_MAXP + (size_t)cs*(NB*HW) + n*HW + h*512;
  #pragma unroll
  for (int p = t; p < 512; p += 256) {
    MAXP[p] = fmaxf(fmaxf(stash[0][p], stash[1][p]),
                    fmaxf(stash[2][p], stash[3][p]));
  }
}

// K6: combine 16 col-strip maxima. grid = 64.
__global__ __launch_bounds__(256) void k_red(float* __restrict__ ws) {
  const int idx = blockIdx.x*256 + threadIdx.x;   // n*HW + p
  float m = ws[OFF_MAXP + idx];
  #pragma unroll
  for (int s = 1; s < NCS; ++s)
    m = fmaxf(m, ws[OFF_MAXP + s*(NB*HW) + idx]);
  ws[OFF_MAXV + idx] = m;
}

// K7: final loss. one block.
__global__ __launch_bounds__(256) void k_final9(const float* __restrict__ ws,
                                                float* __restrict__ out) {
  const int t = threadIdx.x;
  float loss = 0.f;
  for (int n = 0; n < NB; ++n) {
    float s = 0.f;
    for (int k = 0; k < 16; ++k)
      s += __expf(ws[OFF_MAXV + n*HW + k*256 + t]);
    const float tot = blockSum256(s);
    loss += -logf(tot*(1.0f/4096.0f) + kEPS);
  }
  if (t == 0) out[0] = loss*0.25f;
}

extern "C" void kernel_launch(void* const* d_in, const int* in_sizes, int n_in,
                              void* d_out, int out_size, void* d_ws, size_t ws_size,
                              hipStream_t stream) {
  const float* fT = (const float*)d_in[0];
  const float* fI = (const float*)d_in[1];
  float* out = (float*)d_out;
  float* ws  = (float*)d_ws;

  const size_t need_full = (size_t)WS_FLOATS_FULL * sizeof(float);
  if (ws_size < need_full) return;  // ~19 MB

  const ushort* GT = (const ushort*)(ws + OFF_GT);
  const ushort* GI = (const ushort*)(ws + OFF_GI);
  k_mean9 <<<256,  256, 0, stream>>>(fT, ws);
  k_prep9 <<<1024, 256, 0, stream>>>(fT, fI, ws);
  k_gA    <<<512,  256, 0, stream>>>(GT, GI, ws);   // colmax partials
  k_gB    <<<512,  256, 0, stream>>>(GT, GI, ws);   // Wsum partials
  k_gC    <<<512,  256, 0, stream>>>(GT, GI, ws);   // maxv strip partials
  k_red   <<<64,   256, 0, stream>>>(ws);           // strip combine
  k_final9<<<1,    256, 0, stream>>>(ws, out);
}

// Round 12
// 176.421 us; speedup vs baseline: 1.0127x; 1.0127x over previous
//
#include <hip/hip_runtime.h>
#include <cmath>

// CXLoss pipeline, revision 30 == R27 restored verbatim (measured best:
// 173.3us, absmax 0.0). R28 (K_A=2 on proven skeleton, 178.1) and R29
// (single-barrier triple-buffer + setprio, 178.7) both regressed on
// pre-registered failure criteria -- the sweep-structure search is exhausted:
// K_B=1/4blk = LDS-pipe-bound, K_B=2/2blk = latency-bound at 2 waves/SIMD
// with registers capping occupancy (128-reg breg), barrier count and chain
// count both falsified as binders. Locking in the empirical optimum.
// Structure: 3 fused GEMM sweeps (colmax -> Wsum -> rowmax; serial dependency
// chain is algorithmically irreducible), glds16 staging, counted vmcnt(4),
// raw s_barrier pairs, K_B=2, gC with swapped MFMA operands so the
// q-reduction is register-local (fmax chain + one shfl_xor(32)).

#define NB 4
#define CC 256
#define HW 4096
#define NQ0 8    // p-slab loop-split (CMAX/WSUM partials)
#define NCS 16   // q col-strips (MAXP partials)

static constexpr float kEPS = 1e-8f;
static constexpr float kSIG = 0.1f + 1e-8f;

typedef __attribute__((ext_vector_type(8)))  short short8;
typedef __attribute__((ext_vector_type(16))) float f32x16;

// workspace layout (float units)
enum {
  OFF_MEAN = 0,                        // 256 channel means
  OFF_CMAX = 256,                      // NQ0*NB*HW colmax partials
  OFF_WSUM = OFF_CMAX + NQ0*NB*HW,     // NQ0*NB*HW Wsum partials
  OFF_MAXP = OFF_WSUM + NQ0*NB*HW,     // NCS*NB*HW maxv partials (1MB)
  OFF_MAXV = OFF_MAXP + NCS*NB*HW,     // NB*HW maxv
  OFF_GT   = OFF_MAXV + NB*HW,         // NB*HW*CC bf16, fragment-tiled
  OFF_GI   = OFF_GT + NB*HW*CC/2,
  WS_FLOATS_FULL = OFF_GI + NB*HW*CC/2
};

__device__ __forceinline__ ushort cvt_bf16(float x) {
  unsigned u = __float_as_uint(x);
  unsigned r = (u + 0x7fffu + ((u >> 16) & 1u)) >> 16;  // round-nearest-even
  return (ushort)r;
}

__device__ __forceinline__ void glds16(const ushort* g, ushort* l) {
  __builtin_amdgcn_global_load_lds(
      (const __attribute__((address_space(1))) unsigned*)g,
      (__attribute__((address_space(3))) unsigned*)l, 16, 0, 0);
}
__device__ __forceinline__ void s_bar()  { asm volatile("s_barrier" ::: "memory"); }
__device__ __forceinline__ void w_vm4()  { asm volatile("s_waitcnt vmcnt(4)" ::: "memory"); }
__device__ __forceinline__ void w_vm0()  { asm volatile("s_waitcnt vmcnt(0)" ::: "memory"); }
__device__ __forceinline__ void w_lgkm() { asm volatile("s_waitcnt lgkmcnt(0)" ::: "memory"); }

__device__ __forceinline__ float blockSum256(float v) {
  __shared__ float sh[4];
  const int lane = threadIdx.x & 63, wv = threadIdx.x >> 6;
  #pragma unroll
  for (int o = 32; o > 0; o >>= 1) v += __shfl_down(v, o, 64);
  __syncthreads();
  if (lane == 0) sh[wv] = v;
  __syncthreads();
  return sh[0] + sh[1] + sh[2] + sh[3];
}

// K1: per-channel mean of featureT. grid=256
__global__ __launch_bounds__(256) void k_mean9(const float* __restrict__ fT,
                                               float* __restrict__ ws) {
  const int c = blockIdx.x, t = threadIdx.x;
  float s = 0.f;
  for (int n = 0; n < NB; ++n) {
    const float* p = fT + (size_t)(n*CC + c)*HW;
    #pragma unroll
    for (int k = 0; k < 16; ++k) s += p[k*256 + t];
  }
  const float tot = blockSum256(s);
  if (t == 0) ws[OFF_MEAN + c] = tot * (1.0f/16384.0f);
}

// K2: fused normalize + fragment-tiled bf16 write (verified R14 layout):
// offset_ushort(n, r32, kc) = ((n*128 + r32)*16 + kc)*512 + l*8
//   holds X[n][p = r32*32 + (l&31)][c = kc*16 + (l>>5)*8 + j], j<8.
// grid = 2 * NB * 128 = 1024 blocks.
__global__ __launch_bounds__(256) void k_prep9(const float* __restrict__ fT,
                                               const float* __restrict__ fI,
                                               float* __restrict__ ws) {
  __shared__ float stage[32][257];
  __shared__ float prt[8][32];
  __shared__ float sinv[32];
  const int t = threadIdx.x, l = t & 63;
  int bid = blockIdx.x;
  const int tensor = (bid >= 512); bid &= 511;
  const int n   = bid >> 7;
  const int r32 = bid & 127;
  const int p0  = r32 * 32;

  const float* __restrict__ src = tensor ? fI : fT;
  ushort* __restrict__ dst = (ushort*)(ws + (tensor ? OFF_GI : OFF_GT));
  const float* __restrict__ mean = ws + OFF_MEAN;

  const int pl = t & 31, cg = t >> 5;
  float acc = 0.f;
  #pragma unroll
  for (int i = 0; i < 32; ++i) {
    const int c = cg*32 + i;
    const float v = src[((size_t)(n*CC + c))*HW + p0 + pl] - mean[c];
    stage[pl][c] = v;
    acc += v*v;
  }
  prt[cg][pl] = acc;
  __syncthreads();
  if (t < 32) {
    float s = 0.f;
    #pragma unroll
    for (int g = 0; g < 8; ++g) s += prt[g][t];
    sinv[t] = 1.0f/(sqrtf(s) + kEPS);
  }
  __syncthreads();

  const int w = t >> 6, lhi = l >> 5, m = l & 31;
  const float iv = sinv[m];
  #pragma unroll
  for (int i = 0; i < 4; ++i) {
    const int kc = w*4 + i;
    const int cb = kc*16 + lhi*8;
    short8 o;
    #pragma unroll
    for (int j = 0; j < 8; ++j)
      ((ushort*)&o)[j] = cvt_bf16(stage[m][cb + j] * iv);
    *(short8*)(dst + (((size_t)(n*128 + r32)*16 + kc) << 9) + l*8) = o;
  }
}

// ---- shared sweep geometry (K_B=2, glds + counted vmcnt) ----
// L: xcd = L&7, g = L>>3; nh = xcd*4 + (g&3); cs = g>>2.
// n = nh>>3, h = nh&7, col0 = cs*256.
// wave w: B col-tiles RB0 = cs*8+w, RB1 = cs*8+4+w; lane q0 = col0+w*32+ln31,
// q1 = q0+128. Per iter: glds tile -> Ab[iter&1]; 16 kc: 1 ds_read -> 2 MFMA.
// C/D map: col = lane&31, row = (r&3) + 8*(r>>2) + 4*(lane>>5).

// K3a: GEMM sweep + colmax partials. grid 512.
__global__ __launch_bounds__(256, 2) void k_gA(
    const ushort* __restrict__ gA, const ushort* __restrict__ gB,
    float* __restrict__ ws)
{
  __shared__ ushort Ab[2][8192];
  __shared__ float red2[256];

  const int t = threadIdx.x;
  const int w = t >> 6, l = t & 63;
  const int ln31 = l & 31;

  const int L = blockIdx.x;
  const int xcd = L & 7, g = L >> 3;
  const int nh = xcd*4 + (g & 3);
  const int cs = g >> 2;
  const int n = nh >> 3, h = nh & 7;
  const int col0 = cs * 256;

  const ushort* __restrict__ gAn = gA + ((size_t)(n*128 + h*16) << 13);

  // prologue: async-stage tiles 0,1
  #pragma unroll
  for (int i = 0; i < 4; ++i)
    glds16(gAn + (size_t)(i*256 + t)*8, &Ab[0][(i*256 + t)*8]);
  #pragma unroll
  for (int i = 0; i < 4; ++i)
    glds16(gAn + 8192 + (size_t)(i*256 + t)*8, &Ab[1][(i*256 + t)*8]);

  short8 breg0[16], breg1[16];
  {
    const int RB0 = cs*8 + w, RB1 = cs*8 + 4 + w;
    #pragma unroll
    for (int kc = 0; kc < 16; ++kc) {
      breg0[kc] = *(const short8*)(gB + (((size_t)(n*128 + RB0)*16 + kc) << 9) + l*8);
      breg1[kc] = *(const short8*)(gB + (((size_t)(n*128 + RB1)*16 + kc) << 9) + l*8);
    }
  }

  float run0 = -3.0e38f, run1 = -3.0e38f;

  for (int iter = 0; iter < 16; ++iter) {
    if (iter < 15) w_vm4(); else w_vm0();
    s_bar();                                   // Ab[iter&1] staged (all waves)

    const ushort* __restrict__ Abuf = &Ab[iter & 1][0];
    f32x16 acc0, acc1;
    #pragma unroll
    for (int e = 0; e < 16; ++e) { acc0[e] = 0.f; acc1[e] = 0.f; }
    #pragma unroll
    for (int kc = 0; kc < 16; ++kc) {
      const short8 a0 = *(const short8*)&Abuf[kc*512 + l*8];
      acc0 = __builtin_amdgcn_mfma_f32_32x32x16_bf16(a0, breg0[kc], acc0, 0, 0, 0);
      acc1 = __builtin_amdgcn_mfma_f32_32x32x16_bf16(a0, breg1[kc], acc1, 0, 0, 0);
    }
    w_lgkm();
    s_bar();                                   // all waves done reading Ab[iter&1]
    if (iter + 2 < 16) {
      const ushort* __restrict__ src = gAn + (size_t)(iter + 2)*8192;
      ushort* __restrict__ dstl = &Ab[iter & 1][0];
      #pragma unroll
      for (int i = 0; i < 4; ++i)
        glds16(src + (size_t)(i*256 + t)*8, dstl + (i*256 + t)*8);
    }

    #pragma unroll
    for (int r = 0; r < 16; ++r) {
      run0 = fmaxf(run0, acc0[r]);
      run1 = fmaxf(run1, acc1[r]);
    }
  }

  run0 = fmaxf(run0, __shfl_xor(run0, 32, 64));
  run1 = fmaxf(run1, __shfl_xor(run1, 32, 64));
  if (l < 32) {
    red2[w*32 + ln31]       = run0;
    red2[128 + w*32 + ln31] = run1;
  }
  __syncthreads();
  ws[OFF_CMAX + h*(NB*HW) + n*HW + col0 + t] = red2[t];
}

// K3b: GEMM sweep + Wsum partials. Per-lane a,b derived from CMAX.
__global__ __launch_bounds__(256, 2) void k_gB(
    const ushort* __restrict__ gA, const ushort* __restrict__ gB,
    float* __restrict__ ws)
{
  __shared__ ushort Ab[2][8192];
  __shared__ float red2[256];

  const int t = threadIdx.x;
  const int w = t >> 6, l = t & 63;
  const int ln31 = l & 31;

  const int L = blockIdx.x;
  const int xcd = L & 7, g = L >> 3;
  const int nh = xcd*4 + (g & 3);
  const int cs = g >> 2;
  const int n = nh >> 3, h = nh & 7;
  const int col0 = cs * 256;

  const ushort* __restrict__ gAn = gA + ((size_t)(n*128 + h*16) << 13);

  #pragma unroll
  for (int i = 0; i < 4; ++i)
    glds16(gAn + (size_t)(i*256 + t)*8, &Ab[0][(i*256 + t)*8]);
  #pragma unroll
  for (int i = 0; i < 4; ++i)
    glds16(gAn + 8192 + (size_t)(i*256 + t)*8, &Ab[1][(i*256 + t)*8]);

  // per-lane affine coeffs for both q columns (same op order as R24)
  float aq0, bq0, aq1, bq1;
  {
    const int q0 = col0 + w*32 + ln31;
    const int q1 = q0 + 128;
    float cm0 = -3.0e38f, cm1 = -3.0e38f;
    #pragma unroll
    for (int hh = 0; hh < NQ0; ++hh) {
      cm0 = fmaxf(cm0, ws[OFF_CMAX + hh*(NB*HW) + n*HW + q0]);
      cm1 = fmaxf(cm1, ws[OFF_CMAX + hh*(NB*HW) + n*HW + q1]);
    }
    const float i0 = 1.0f/(2.0f*(0.5f*(1.0f - cm0) + kEPS));
    const float i1 = 1.0f/(2.0f*(0.5f*(1.0f - cm1) + kEPS));
    bq0 = i0 / kSIG; aq0 = (1.0f - i0) / kSIG;
    bq1 = i1 / kSIG; aq1 = (1.0f - i1) / kSIG;
  }

  short8 breg0[16], breg1[16];
  {
    const int RB0 = cs*8 + w, RB1 = cs*8 + 4 + w;
    #pragma unroll
    for (int kc = 0; kc < 16; ++kc) {
      breg0[kc] = *(const short8*)(gB + (((size_t)(n*128 + RB0)*16 + kc) << 9) + l*8);
      breg1[kc] = *(const short8*)(gB + (((size_t)(n*128 + RB1)*16 + kc) << 9) + l*8);
    }
  }

  float ws0 = 0.f, ws1 = 0.f;

  for (int iter = 0; iter < 16; ++iter) {
    if (iter < 15) w_vm4(); else w_vm0();
    s_bar();

    const ushort* __restrict__ Abuf = &Ab[iter & 1][0];
    f32x16 acc0, acc1;
    #pragma unroll
    for (int e = 0; e < 16; ++e) { acc0[e] = 0.f; acc1[e] = 0.f; }
    #pragma unroll
    for (int kc = 0; kc < 16; ++kc) {
      const short8 a0 = *(const short8*)&Abuf[kc*512 + l*8];
      acc0 = __builtin_amdgcn_mfma_f32_32x32x16_bf16(a0, breg0[kc], acc0, 0, 0, 0);
      acc1 = __builtin_amdgcn_mfma_f32_32x32x16_bf16(a0, breg1[kc], acc1, 0, 0, 0);
    }
    w_lgkm();
    s_bar();
    if (iter + 2 < 16) {
      const ushort* __restrict__ src = gAn + (size_t)(iter + 2)*8192;
      ushort* __restrict__ dstl = &Ab[iter & 1][0];
      #pragma unroll
      for (int i = 0; i < 4; ++i)
        glds16(src + (size_t)(i*256 + t)*8, dstl + (i*256 + t)*8);
    }

    #pragma unroll
    for (int r = 0; r < 16; ++r) {
      ws0 += __expf(fmaf(bq0, acc0[r], aq0));
      ws1 += __expf(fmaf(bq1, acc1[r], aq1));
    }
  }

  ws0 += __shfl_xor(ws0, 32, 64);
  ws1 += __shfl_xor(ws1, 32, 64);
  if (l < 32) {
    red2[w*32 + ln31]       = ws0;
    red2[128 + w*32 + ln31] = ws1;
  }
  __syncthreads();
  ws[OFF_WSUM + h*(NB*HW) + n*HW + col0 + t] = red2[t];
}

// K3c: GEMM sweep + row-max (maxv) partials, SWAPPED operands:
// acc = mfma(breg, afrag) -> col(lane&31) = p, reg = q. Max over q is an
// in-register fmax chain + one shfl_xor(32). gamma/beta per q-row from a
// per-block LDS table (exact k_gb9 formula/order). Per-wave maxima stashed
// in LDS; MAXP written once at the end.
__global__ __launch_bounds__(256, 2) void k_gC(
    const ushort* __restrict__ gA, const ushort* __restrict__ gB,
    float* __restrict__ ws)
{
  __shared__ ushort Ab[2][8192];
  __shared__ float gam_s[256], bet_s[256];
  __shared__ float stash[4][512];   // 8KB: per-wave p-maxima

  const int t = threadIdx.x;
  const int w = t >> 6, l = t & 63;
  const int ln31 = l & 31, lhi = l >> 5;

  const int L = blockIdx.x;
  const int xcd = L & 7, g = L >> 3;
  const int nh = xcd*4 + (g & 3);
  const int cs = g >> 2;
  const int n = nh >> 3, h = nh & 7;
  const int col0 = cs * 256;

  const ushort* __restrict__ gAn = gA + ((size_t)(n*128 + h*16) << 13);

  #pragma unroll
  for (int i = 0; i < 4; ++i)
    glds16(gAn + (size_t)(i*256 + t)*8, &Ab[0][(i*256 + t)*8]);
  #pragma unroll
  for (int i = 0; i < 4; ++i)
    glds16(gAn + 8192 + (size_t)(i*256 + t)*8, &Ab[1][(i*256 + t)*8]);

  // gamma/beta table for this block's 256 q (formula/order == old k_gb9)
  {
    const int idx = n*HW + col0 + t;
    float cm = -3.0e38f;
    #pragma unroll
    for (int hh = 0; hh < NQ0; ++hh)
      cm = fmaxf(cm, ws[OFF_CMAX + hh*(NB*HW) + idx]);
    float sw = 0.f;
    #pragma unroll
    for (int hh = 0; hh < NQ0; ++hh)
      sw += ws[OFF_WSUM + hh*(NB*HW) + idx];
    const float i0 = 1.0f/(2.0f*(0.5f*(1.0f - cm) + kEPS));
    bet_s[t] = i0 / kSIG;
    gam_s[t] = (1.0f - i0) / kSIG - logf(sw + kEPS);
  }

  short8 breg0[16], breg1[16];
  {
    const int RB0 = cs*8 + w, RB1 = cs*8 + 4 + w;
    #pragma unroll
    for (int kc = 0; kc < 16; ++kc) {
      breg0[kc] = *(const short8*)(gB + (((size_t)(n*128 + RB0)*16 + kc) << 9) + l*8);
      breg1[kc] = *(const short8*)(gB + (((size_t)(n*128 + RB1)*16 + kc) << 9) + l*8);
    }
  }
  __syncthreads();   // gam/bet table ready (also covers stash init ordering)

  for (int iter = 0; iter < 16; ++iter) {
    if (iter < 15) w_vm4(); else w_vm0();
    s_bar();                                   // Ab[iter&1] staged

    const ushort* __restrict__ Abuf = &Ab[iter & 1][0];
    f32x16 accq0, accq1;                       // rows = q, cols = p (swapped)
    #pragma unroll
    for (int e = 0; e < 16; ++e) { accq0[e] = 0.f; accq1[e] = 0.f; }
    #pragma unroll
    for (int kc = 0; kc < 16; ++kc) {
      const short8 a0 = *(const short8*)&Abuf[kc*512 + l*8];
      accq0 = __builtin_amdgcn_mfma_f32_32x32x16_bf16(breg0[kc], a0, accq0, 0, 0, 0);
      accq1 = __builtin_amdgcn_mfma_f32_32x32x16_bf16(breg1[kc], a0, accq1, 0, 0, 0);
    }
    w_lgkm();
    s_bar();
    if (iter + 2 < 16) {
      const ushort* __restrict__ src = gAn + (size_t)(iter + 2)*8192;
      ushort* __restrict__ dstl = &Ab[iter & 1][0];
      #pragma unroll
      for (int i = 0; i < 4; ++i)
        glds16(src + (size_t)(i*256 + t)*8, dstl + (i*256 + t)*8);
    }

    // epilogue: lane holds p = iter*32 + ln31; 16 q-rows per acc tile.
    float m = -3.0e38f;
    #pragma unroll
    for (int r = 0; r < 16; ++r) {
      const int row = (r & 3) + 8*(r >> 2) + 4*lhi;
      const float g0v = gam_s[w*32 + row],       b0v = bet_s[w*32 + row];
      const float g1v = gam_s[128 + w*32 + row], b1v = bet_s[128 + w*32 + row];
      m = fmaxf(m, fmaf(b0v, accq0[r], g0v));
      m = fmaxf(m, fmaf(b1v, accq1[r], g1v));
    }
    m = fmaxf(m, __shfl_xor(m, 32, 64));       // merge lhi q-halves
    if (l < 32) stash[w][iter*32 + ln31] = m;  // p-local = iter*32 + ln31
  }

  __syncthreads();
  float* __restrict__ MAXP = ws + OFF_MAXP + (size_t)cs*(NB*HW) + n*HW + h*512;
  #pragma unroll
  for (int p = t; p < 512; p += 256) {
    MAXP[p] = fmaxf(fmaxf(stash[0][p], stash[1][p]),
                    fmaxf(stash[2][p], stash[3][p]));
  }
}

// K6: combine 16 col-strip maxima. grid = 64.
__global__ __launch_bounds__(256) void k_red(float* __restrict__ ws) {
  const int idx = blockIdx.x*256 + threadIdx.x;   // n*HW + p
  float m = ws[OFF_MAXP + idx];
  #pragma unroll
  for (int s = 1; s < NCS; ++s)
    m = fmaxf(m, ws[OFF_MAXP + s*(NB*HW) + idx]);
  ws[OFF_MAXV + idx] = m;
}

// K7: final loss. one block.
__global__ __launch_bounds__(256) void k_final9(const float* __restrict__ ws,
                                                float* __restrict__ out) {
  const int t = threadIdx.x;
  float loss = 0.f;
  for (int n = 0; n < NB; ++n) {
    float s = 0.f;
    for (int k = 0; k < 16; ++k)
      s += __expf(ws[OFF_MAXV + n*HW + k*256 + t]);
    const float tot = blockSum256(s);
    loss += -logf(tot*(1.0f/4096.0f) + kEPS);
  }
  if (t == 0) out[0] = loss*0.25f;
}

extern "C" void kernel_launch(void* const* d_in, const int* in_sizes, int n_in,
                              void* d_out, int out_size, void* d_ws, size_t ws_size,
                              hipStream_t stream) {
  const float* fT = (const float*)d_in[0];
  const float* fI = (const float*)d_in[1];
  float* out = (float*)d_out;
  float* ws  = (float*)d_ws;

  const size_t need_full = (size_t)WS_FLOATS_FULL * sizeof(float);
  if (ws_size < need_full) return;  // ~19 MB

  const ushort* GT = (const ushort*)(ws + OFF_GT);
  const ushort* GI = (const ushort*)(ws + OFF_GI);
  k_mean9 <<<256,  256, 0, stream>>>(fT, ws);
  k_prep9 <<<1024, 256, 0, stream>>>(fT, fI, ws);
  k_gA    <<<512,  256, 0, stream>>>(GT, GI, ws);   // colmax partials
  k_gB    <<<512,  256, 0, stream>>>(GT, GI, ws);   // Wsum partials
  k_gC    <<<512,  256, 0, stream>>>(GT, GI, ws);   // maxv strip partials
  k_red   <<<64,   256, 0, stream>>>(ws);           // strip combine
  k_final9<<<1,    256, 0, stream>>>(ws, out);
}

// Round 13
// 171.753 us; speedup vs baseline: 1.0403x; 1.0272x over previous
//
#include <hip/hip_runtime.h>
#include <cmath>

// CXLoss pipeline, revision 31: R27 sweeps (measured best 173.3-176.4, noise
// band +-3us) + launch-count cleanup. R12 showed identical code re-measures
// within +-3us -> R28/R29 "regressions" were noise; structure is at plateau.
// Residual addressable cost: ~30us of launch gaps/small kernels across 7
// dispatches. This rev deletes k_red: k_gC combines strip maxima into MAXV
// via order-preserving-encoded atomicMax (enc(f)=msb?~bits:bits|0x80000000;
// strict total order == float order, fmax exact-assoc -> bit-identical to
// the old deterministic k_red). MAXV init = enc(-inf), written by 64 of
// k_prep9's blocks (stream-ordered before gC). k_final9 decodes inline.
// All sweeps byte-identical to R27.

#define NB 4
#define CC 256
#define HW 4096
#define NQ0 8    // p-slab loop-split (CMAX/WSUM partials)

static constexpr float kEPS = 1e-8f;
static constexpr float kSIG = 0.1f + 1e-8f;

typedef __attribute__((ext_vector_type(8)))  short short8;
typedef __attribute__((ext_vector_type(16))) float f32x16;

// workspace layout (float units)
enum {
  OFF_MEAN = 0,                        // 256 channel means
  OFF_CMAX = 256,                      // NQ0*NB*HW colmax partials
  OFF_WSUM = OFF_CMAX + NQ0*NB*HW,     // NQ0*NB*HW Wsum partials
  OFF_MAXV = OFF_WSUM + NQ0*NB*HW,     // NB*HW maxv (ENCODED uint, atomicMax)
  OFF_GT   = OFF_MAXV + NB*HW,         // NB*HW*CC bf16, fragment-tiled
  OFF_GI   = OFF_GT + NB*HW*CC/2,
  WS_FLOATS_FULL = OFF_GI + NB*HW*CC/2
};

static constexpr unsigned kEncNegInf = 0x007fffffu;  // enc(-inf)

__device__ __forceinline__ unsigned enc_f32(float f) {
  const unsigned u = __float_as_uint(f);
  return (u & 0x80000000u) ? ~u : (u | 0x80000000u);
}
__device__ __forceinline__ float dec_f32(unsigned e) {
  const unsigned u = (e & 0x80000000u) ? (e & 0x7fffffffu) : ~e;
  return __uint_as_float(u);
}

__device__ __forceinline__ ushort cvt_bf16(float x) {
  unsigned u = __float_as_uint(x);
  unsigned r = (u + 0x7fffu + ((u >> 16) & 1u)) >> 16;  // round-nearest-even
  return (ushort)r;
}

__device__ __forceinline__ void glds16(const ushort* g, ushort* l) {
  __builtin_amdgcn_global_load_lds(
      (const __attribute__((address_space(1))) unsigned*)g,
      (__attribute__((address_space(3))) unsigned*)l, 16, 0, 0);
}
__device__ __forceinline__ void s_bar()  { asm volatile("s_barrier" ::: "memory"); }
__device__ __forceinline__ void w_vm4()  { asm volatile("s_waitcnt vmcnt(4)" ::: "memory"); }
__device__ __forceinline__ void w_vm0()  { asm volatile("s_waitcnt vmcnt(0)" ::: "memory"); }
__device__ __forceinline__ void w_lgkm() { asm volatile("s_waitcnt lgkmcnt(0)" ::: "memory"); }

__device__ __forceinline__ float blockSum256(float v) {
  __shared__ float sh[4];
  const int lane = threadIdx.x & 63, wv = threadIdx.x >> 6;
  #pragma unroll
  for (int o = 32; o > 0; o >>= 1) v += __shfl_down(v, o, 64);
  __syncthreads();
  if (lane == 0) sh[wv] = v;
  __syncthreads();
  return sh[0] + sh[1] + sh[2] + sh[3];
}

// K1: per-channel mean of featureT. grid=256
__global__ __launch_bounds__(256) void k_mean9(const float* __restrict__ fT,
                                               float* __restrict__ ws) {
  const int c = blockIdx.x, t = threadIdx.x;
  float s = 0.f;
  for (int n = 0; n < NB; ++n) {
    const float* p = fT + (size_t)(n*CC + c)*HW;
    #pragma unroll
    for (int k = 0; k < 16; ++k) s += p[k*256 + t];
  }
  const float tot = blockSum256(s);
  if (t == 0) ws[OFF_MEAN + c] = tot * (1.0f/16384.0f);
}

// K2: fused normalize + fragment-tiled bf16 write (verified R14 layout):
// offset_ushort(n, r32, kc) = ((n*128 + r32)*16 + kc)*512 + l*8
//   holds X[n][p = r32*32 + (l&31)][c = kc*16 + (l>>5)*8 + j], j<8.
// grid = 2 * NB * 128 = 1024 blocks. Blocks 0..63 also init MAXV=enc(-inf).
__global__ __launch_bounds__(256) void k_prep9(const float* __restrict__ fT,
                                               const float* __restrict__ fI,
                                               float* __restrict__ ws) {
  __shared__ float stage[32][257];
  __shared__ float prt[8][32];
  __shared__ float sinv[32];
  const int t = threadIdx.x, l = t & 63;
  const int obid = blockIdx.x;
  int bid = obid;
  const int tensor = (bid >= 512); bid &= 511;
  const int n   = bid >> 7;
  const int r32 = bid & 127;
  const int p0  = r32 * 32;

  if (obid < 64)   // init encoded MAXV (runs before k_gC in stream order)
    ((unsigned*)(ws + OFF_MAXV))[obid*256 + t] = kEncNegInf;

  const float* __restrict__ src = tensor ? fI : fT;
  ushort* __restrict__ dst = (ushort*)(ws + (tensor ? OFF_GI : OFF_GT));
  const float* __restrict__ mean = ws + OFF_MEAN;

  const int pl = t & 31, cg = t >> 5;
  float acc = 0.f;
  #pragma unroll
  for (int i = 0; i < 32; ++i) {
    const int c = cg*32 + i;
    const float v = src[((size_t)(n*CC + c))*HW + p0 + pl] - mean[c];
    stage[pl][c] = v;
    acc += v*v;
  }
  prt[cg][pl] = acc;
  __syncthreads();
  if (t < 32) {
    float s = 0.f;
    #pragma unroll
    for (int g = 0; g < 8; ++g) s += prt[g][t];
    sinv[t] = 1.0f/(sqrtf(s) + kEPS);
  }
  __syncthreads();

  const int w = t >> 6, lhi = l >> 5, m = l & 31;
  const float iv = sinv[m];
  #pragma unroll
  for (int i = 0; i < 4; ++i) {
    const int kc = w*4 + i;
    const int cb = kc*16 + lhi*8;
    short8 o;
    #pragma unroll
    for (int j = 0; j < 8; ++j)
      ((ushort*)&o)[j] = cvt_bf16(stage[m][cb + j] * iv);
    *(short8*)(dst + (((size_t)(n*128 + r32)*16 + kc) << 9) + l*8) = o;
  }
}

// ---- shared sweep geometry (K_B=2, glds + counted vmcnt) ----
// L: xcd = L&7, g = L>>3; nh = xcd*4 + (g&3); cs = g>>2.
// n = nh>>3, h = nh&7, col0 = cs*256.
// wave w: B col-tiles RB0 = cs*8+w, RB1 = cs*8+4+w; lane q0 = col0+w*32+ln31,
// q1 = q0+128. Per iter: glds tile -> Ab[iter&1]; 16 kc: 1 ds_read -> 2 MFMA.
// C/D map: col = lane&31, row = (r&3) + 8*(r>>2) + 4*(lane>>5).

// K3a: GEMM sweep + colmax partials. grid 512.
__global__ __launch_bounds__(256, 2) void k_gA(
    const ushort* __restrict__ gA, const ushort* __restrict__ gB,
    float* __restrict__ ws)
{
  __shared__ ushort Ab[2][8192];
  __shared__ float red2[256];

  const int t = threadIdx.x;
  const int w = t >> 6, l = t & 63;
  const int ln31 = l & 31;

  const int L = blockIdx.x;
  const int xcd = L & 7, g = L >> 3;
  const int nh = xcd*4 + (g & 3);
  const int cs = g >> 2;
  const int n = nh >> 3, h = nh & 7;
  const int col0 = cs * 256;

  const ushort* __restrict__ gAn = gA + ((size_t)(n*128 + h*16) << 13);

  // prologue: async-stage tiles 0,1
  #pragma unroll
  for (int i = 0; i < 4; ++i)
    glds16(gAn + (size_t)(i*256 + t)*8, &Ab[0][(i*256 + t)*8]);
  #pragma unroll
  for (int i = 0; i < 4; ++i)
    glds16(gAn + 8192 + (size_t)(i*256 + t)*8, &Ab[1][(i*256 + t)*8]);

  short8 breg0[16], breg1[16];
  {
    const int RB0 = cs*8 + w, RB1 = cs*8 + 4 + w;
    #pragma unroll
    for (int kc = 0; kc < 16; ++kc) {
      breg0[kc] = *(const short8*)(gB + (((size_t)(n*128 + RB0)*16 + kc) << 9) + l*8);
      breg1[kc] = *(const short8*)(gB + (((size_t)(n*128 + RB1)*16 + kc) << 9) + l*8);
    }
  }

  float run0 = -3.0e38f, run1 = -3.0e38f;

  for (int iter = 0; iter < 16; ++iter) {
    if (iter < 15) w_vm4(); else w_vm0();
    s_bar();                                   // Ab[iter&1] staged (all waves)

    const ushort* __restrict__ Abuf = &Ab[iter & 1][0];
    f32x16 acc0, acc1;
    #pragma unroll
    for (int e = 0; e < 16; ++e) { acc0[e] = 0.f; acc1[e] = 0.f; }
    #pragma unroll
    for (int kc = 0; kc < 16; ++kc) {
      const short8 a0 = *(const short8*)&Abuf[kc*512 + l*8];
      acc0 = __builtin_amdgcn_mfma_f32_32x32x16_bf16(a0, breg0[kc], acc0, 0, 0, 0);
      acc1 = __builtin_amdgcn_mfma_f32_32x32x16_bf16(a0, breg1[kc], acc1, 0, 0, 0);
    }
    w_lgkm();
    s_bar();                                   // all waves done reading Ab[iter&1]
    if (iter + 2 < 16) {
      const ushort* __restrict__ src = gAn + (size_t)(iter + 2)*8192;
      ushort* __restrict__ dstl = &Ab[iter & 1][0];
      #pragma unroll
      for (int i = 0; i < 4; ++i)
        glds16(src + (size_t)(i*256 + t)*8, dstl + (i*256 + t)*8);
    }

    #pragma unroll
    for (int r = 0; r < 16; ++r) {
      run0 = fmaxf(run0, acc0[r]);
      run1 = fmaxf(run1, acc1[r]);
    }
  }

  run0 = fmaxf(run0, __shfl_xor(run0, 32, 64));
  run1 = fmaxf(run1, __shfl_xor(run1, 32, 64));
  if (l < 32) {
    red2[w*32 + ln31]       = run0;
    red2[128 + w*32 + ln31] = run1;
  }
  __syncthreads();
  ws[OFF_CMAX + h*(NB*HW) + n*HW + col0 + t] = red2[t];
}

// K3b: GEMM sweep + Wsum partials. Per-lane a,b derived from CMAX.
__global__ __launch_bounds__(256, 2) void k_gB(
    const ushort* __restrict__ gA, const ushort* __restrict__ gB,
    float* __restrict__ ws)
{
  __shared__ ushort Ab[2][8192];
  __shared__ float red2[256];

  const int t = threadIdx.x;
  const int w = t >> 6, l = t & 63;
  const int ln31 = l & 31;

  const int L = blockIdx.x;
  const int xcd = L & 7, g = L >> 3;
  const int nh = xcd*4 + (g & 3);
  const int cs = g >> 2;
  const int n = nh >> 3, h = nh & 7;
  const int col0 = cs * 256;

  const ushort* __restrict__ gAn = gA + ((size_t)(n*128 + h*16) << 13);

  #pragma unroll
  for (int i = 0; i < 4; ++i)
    glds16(gAn + (size_t)(i*256 + t)*8, &Ab[0][(i*256 + t)*8]);
  #pragma unroll
  for (int i = 0; i < 4; ++i)
    glds16(gAn + 8192 + (size_t)(i*256 + t)*8, &Ab[1][(i*256 + t)*8]);

  // per-lane affine coeffs for both q columns (same op order as R24)
  float aq0, bq0, aq1, bq1;
  {
    const int q0 = col0 + w*32 + ln31;
    const int q1 = q0 + 128;
    float cm0 = -3.0e38f, cm1 = -3.0e38f;
    #pragma unroll
    for (int hh = 0; hh < NQ0; ++hh) {
      cm0 = fmaxf(cm0, ws[OFF_CMAX + hh*(NB*HW) + n*HW + q0]);
      cm1 = fmaxf(cm1, ws[OFF_CMAX + hh*(NB*HW) + n*HW + q1]);
    }
    const float i0 = 1.0f/(2.0f*(0.5f*(1.0f - cm0) + kEPS));
    const float i1 = 1.0f/(2.0f*(0.5f*(1.0f - cm1) + kEPS));
    bq0 = i0 / kSIG; aq0 = (1.0f - i0) / kSIG;
    bq1 = i1 / kSIG; aq1 = (1.0f - i1) / kSIG;
  }

  short8 breg0[16], breg1[16];
  {
    const int RB0 = cs*8 + w, RB1 = cs*8 + 4 + w;
    #pragma unroll
    for (int kc = 0; kc < 16; ++kc) {
      breg0[kc] = *(const short8*)(gB + (((size_t)(n*128 + RB0)*16 + kc) << 9) + l*8);
      breg1[kc] = *(const short8*)(gB + (((size_t)(n*128 + RB1)*16 + kc) << 9) + l*8);
    }
  }

  float ws0 = 0.f, ws1 = 0.f;

  for (int iter = 0; iter < 16; ++iter) {
    if (iter < 15) w_vm4(); else w_vm0();
    s_bar();

    const ushort* __restrict__ Abuf = &Ab[iter & 1][0];
    f32x16 acc0, acc1;
    #pragma unroll
    for (int e = 0; e < 16; ++e) { acc0[e] = 0.f; acc1[e] = 0.f; }
    #pragma unroll
    for (int kc = 0; kc < 16; ++kc) {
      const short8 a0 = *(const short8*)&Abuf[kc*512 + l*8];
      acc0 = __builtin_amdgcn_mfma_f32_32x32x16_bf16(a0, breg0[kc], acc0, 0, 0, 0);
      acc1 = __builtin_amdgcn_mfma_f32_32x32x16_bf16(a0, breg1[kc], acc1, 0, 0, 0);
    }
    w_lgkm();
    s_bar();
    if (iter + 2 < 16) {
      const ushort* __restrict__ src = gAn + (size_t)(iter + 2)*8192;
      ushort* __restrict__ dstl = &Ab[iter & 1][0];
      #pragma unroll
      for (int i = 0; i < 4; ++i)
        glds16(src + (size_t)(i*256 + t)*8, dstl + (i*256 + t)*8);
    }

    #pragma unroll
    for (int r = 0; r < 16; ++r) {
      ws0 += __expf(fmaf(bq0, acc0[r], aq0));
      ws1 += __expf(fmaf(bq1, acc1[r], aq1));
    }
  }

  ws0 += __shfl_xor(ws0, 32, 64);
  ws1 += __shfl_xor(ws1, 32, 64);
  if (l < 32) {
    red2[w*32 + ln31]       = ws0;
    red2[128 + w*32 + ln31] = ws1;
  }
  __syncthreads();
  ws[OFF_WSUM + h*(NB*HW) + n*HW + col0 + t] = red2[t];
}

// K3c: GEMM sweep + row-max (maxv), SWAPPED operands (R27 scheme):
// acc = mfma(breg, afrag) -> col(lane&31) = p, reg = q. Max over q is an
// in-register fmax chain + one shfl_xor(32). gamma/beta per q-row from a
// per-block LDS table. Strip maxima combined into MAXV via encoded
// atomicMax (replaces k_red; fmax exact-assoc -> order-independent).
__global__ __launch_bounds__(256, 2) void k_gC(
    const ushort* __restrict__ gA, const ushort* __restrict__ gB,
    float* __restrict__ ws)
{
  __shared__ ushort Ab[2][8192];
  __shared__ float gam_s[256], bet_s[256];
  __shared__ float stash[4][512];   // 8KB: per-wave p-maxima

  const int t = threadIdx.x;
  const int w = t >> 6, l = t & 63;
  const int ln31 = l & 31, lhi = l >> 5;

  const int L = blockIdx.x;
  const int xcd = L & 7, g = L >> 3;
  const int nh = xcd*4 + (g & 3);
  const int cs = g >> 2;
  const int n = nh >> 3, h = nh & 7;
  const int col0 = cs * 256;

  const ushort* __restrict__ gAn = gA + ((size_t)(n*128 + h*16) << 13);

  #pragma unroll
  for (int i = 0; i < 4; ++i)
    glds16(gAn + (size_t)(i*256 + t)*8, &Ab[0][(i*256 + t)*8]);
  #pragma unroll
  for (int i = 0; i < 4; ++i)
    glds16(gAn + 8192 + (size_t)(i*256 + t)*8, &Ab[1][(i*256 + t)*8]);

  // gamma/beta table for this block's 256 q (formula/order == old k_gb9)
  {
    const int idx = n*HW + col0 + t;
    float cm = -3.0e38f;
    #pragma unroll
    for (int hh = 0; hh < NQ0; ++hh)
      cm = fmaxf(cm, ws[OFF_CMAX + hh*(NB*HW) + idx]);
    float sw = 0.f;
    #pragma unroll
    for (int hh = 0; hh < NQ0; ++hh)
      sw += ws[OFF_WSUM + hh*(NB*HW) + idx];
    const float i0 = 1.0f/(2.0f*(0.5f*(1.0f - cm) + kEPS));
    bet_s[t] = i0 / kSIG;
    gam_s[t] = (1.0f - i0) / kSIG - logf(sw + kEPS);
  }

  short8 breg0[16], breg1[16];
  {
    const int RB0 = cs*8 + w, RB1 = cs*8 + 4 + w;
    #pragma unroll
    for (int kc = 0; kc < 16; ++kc) {
      breg0[kc] = *(const short8*)(gB + (((size_t)(n*128 + RB0)*16 + kc) << 9) + l*8);
      breg1[kc] = *(const short8*)(gB + (((size_t)(n*128 + RB1)*16 + kc) << 9) + l*8);
    }
  }
  __syncthreads();   // gam/bet table ready (also covers stash init ordering)

  for (int iter = 0; iter < 16; ++iter) {
    if (iter < 15) w_vm4(); else w_vm0();
    s_bar();                                   // Ab[iter&1] staged

    const ushort* __restrict__ Abuf = &Ab[iter & 1][0];
    f32x16 accq0, accq1;                       // rows = q, cols = p (swapped)
    #pragma unroll
    for (int e = 0; e < 16; ++e) { accq0[e] = 0.f; accq1[e] = 0.f; }
    #pragma unroll
    for (int kc = 0; kc < 16; ++kc) {
      const short8 a0 = *(const short8*)&Abuf[kc*512 + l*8];
      accq0 = __builtin_amdgcn_mfma_f32_32x32x16_bf16(breg0[kc], a0, accq0, 0, 0, 0);
      accq1 = __builtin_amdgcn_mfma_f32_32x32x16_bf16(breg1[kc], a0, accq1, 0, 0, 0);
    }
    w_lgkm();
    s_bar();
    if (iter + 2 < 16) {
      const ushort* __restrict__ src = gAn + (size_t)(iter + 2)*8192;
      ushort* __restrict__ dstl = &Ab[iter & 1][0];
      #pragma unroll
      for (int i = 0; i < 4; ++i)
        glds16(src + (size_t)(i*256 + t)*8, dstl + (i*256 + t)*8);
    }

    // epilogue: lane holds p = iter*32 + ln31; 16 q-rows per acc tile.
    float m = -3.0e38f;
    #pragma unroll
    for (int r = 0; r < 16; ++r) {
      const int row = (r & 3) + 8*(r >> 2) + 4*lhi;
      const float g0v = gam_s[w*32 + row],       b0v = bet_s[w*32 + row];
      const float g1v = gam_s[128 + w*32 + row], b1v = bet_s[128 + w*32 + row];
      m = fmaxf(m, fmaf(b0v, accq0[r], g0v));
      m = fmaxf(m, fmaf(b1v, accq1[r], g1v));
    }
    m = fmaxf(m, __shfl_xor(m, 32, 64));       // merge lhi q-halves
    if (l < 32) stash[w][iter*32 + ln31] = m;  // p-local = iter*32 + ln31
  }

  __syncthreads();
  unsigned* __restrict__ MV = (unsigned*)(ws + OFF_MAXV) + n*HW + h*512;
  #pragma unroll
  for (int p = t; p < 512; p += 256) {
    const float m = fmaxf(fmaxf(stash[0][p], stash[1][p]),
                          fmaxf(stash[2][p], stash[3][p]));
    atomicMax(&MV[p], enc_f32(m));
  }
}

// K7: final loss. one block. Decodes MAXV.
__global__ __launch_bounds__(256) void k_final9(const float* __restrict__ ws,
                                                float* __restrict__ out) {
  const int t = threadIdx.x;
  const unsigned* __restrict__ MV = (const unsigned*)(ws + OFF_MAXV);
  float loss = 0.f;
  for (int n = 0; n < NB; ++n) {
    float s = 0.f;
    for (int k = 0; k < 16; ++k)
      s += __expf(dec_f32(MV[n*HW + k*256 + t]));
    const float tot = blockSum256(s);
    loss += -logf(tot*(1.0f/4096.0f) + kEPS);
  }
  if (t == 0) out[0] = loss*0.25f;
}

extern "C" void kernel_launch(void* const* d_in, const int* in_sizes, int n_in,
                              void* d_out, int out_size, void* d_ws, size_t ws_size,
                              hipStream_t stream) {
  const float* fT = (const float*)d_in[0];
  const float* fI = (const float*)d_in[1];
  float* out = (float*)d_out;
  float* ws  = (float*)d_ws;

  const size_t need_full = (size_t)WS_FLOATS_FULL * sizeof(float);
  if (ws_size < need_full) return;  // ~18 MB

  const ushort* GT = (const ushort*)(ws + OFF_GT);
  const ushort* GI = (const ushort*)(ws + OFF_GI);
  k_mean9 <<<256,  256, 0, stream>>>(fT, ws);
  k_prep9 <<<1024, 256, 0, stream>>>(fT, fI, ws);   // + MAXV init
  k_gA    <<<512,  256, 0, stream>>>(GT, GI, ws);   // colmax partials
  k_gB    <<<512,  256, 0, stream>>>(GT, GI, ws);   // Wsum partials
  k_gC    <<<512,  256, 0, stream>>>(GT, GI, ws);   // maxv via atomicMax
  k_final9<<<1,    256, 0, stream>>>(ws, out);
}